// Round 10
// baseline (348.941 us; speedup 1.0000x reference)
//
#include <hip/hip_runtime.h>
#include <math.h>

// LSTM B=1024,T=512,IN=16,H=64,OUT=8, gates i,f,g,o.
// R10: TWO independent recurrence streams per wave. R9 (248us) = 1163
// cyc/step with only ~630 modeled: ~500 cyc of dependency holes at
// 1 wave/SIMD. Wall = 512 x chain, so co-residency can't help; instead each
// wave now carries two batch-groups (g0: cols m&1 -> batches {0,1}, g1 ->
// {2,3}; replica rho=(m>>1)&3 picks C-row; writer lanes m<8). One round =
// one timestep for BOTH groups, one lite barrier: g1's MFMA/trans work
// fills g0's latency holes. x-acc ping-pong (bias in C operand) keeps
// x-MFMAs off the h-critical path. Per round: 24 MFMA (384 pipe) || 20
// trans (320 pipe) -> ~2x work in ~1.1x round time vs R9.
// Grid 256 blocks x 256 thr (BT=4), fp16 weights pinned, hbuf stride 72.

#define LSTM_T 512
#define LSTM_IN 16
#define LSTM_H 64
#define LSTM_OUT 8
#define BT 4
#define HSTRIDE 72         // halves per batch row: 64 h + 8 pad (bank spread)

#define L2E   1.44269504088896340736f
#define L2E2  2.88539008177792681472f

typedef _Float16 half8  __attribute__((ext_vector_type(8)));
typedef float    floatx4 __attribute__((ext_vector_type(4)));

static __device__ __forceinline__ float fast_rcp(float x) { return __builtin_amdgcn_rcpf(x); }
static __device__ __forceinline__ float fast_exp2(float x) { return __builtin_amdgcn_exp2f(x); }
static __device__ __forceinline__ float sigm2(float p) { return fast_rcp(1.0f + fast_exp2(-p)); }
static __device__ __forceinline__ float tanh2(float p) {
    return fmaf(-2.0f, fast_rcp(1.0f + fast_exp2(p)), 1.0f);
}
static __device__ __forceinline__ void pin4(int4& v) {
    asm volatile("" : "+v"(v.x), "+v"(v.y), "+v"(v.z), "+v"(v.w));
}
static __device__ __forceinline__ void pinf4(float4& v) {
    asm volatile("" : "+v"(v.x), "+v"(v.y), "+v"(v.z), "+v"(v.w));
}
static __device__ __forceinline__ void lite_barrier() {
    asm volatile("s_waitcnt lgkmcnt(0)\n\ts_barrier" ::: "memory");
}
static __device__ __forceinline__ unsigned pk2h(float a, float b) {
    return __builtin_bit_cast(unsigned, __builtin_amdgcn_cvt_pkrtz(a, b));
}
static __device__ __forceinline__ half8 to_h8(float4 a, float4 b) {
    uint4 u = make_uint4(pk2h(a.x, a.y), pk2h(a.z, a.w), pk2h(b.x, b.y), pk2h(b.z, b.w));
    return __builtin_bit_cast(half8, u);
}
static __device__ __forceinline__ int4 cvt8h(float4 a, float4 b, float sc) {
    float4 as = make_float4(a.x * sc, a.y * sc, a.z * sc, a.w * sc);
    float4 bs = make_float4(b.x * sc, b.y * sc, b.z * sc, b.w * sc);
    return __builtin_bit_cast(int4, to_h8(as, bs));
}
static __device__ __forceinline__ float4 ld4(const float* p) {
    return *reinterpret_cast<const float4*>(p);
}
static __device__ __forceinline__ float sel4(floatx4 v, bool r0, bool r1) {
    float lo = r0 ? v[1] : v[0];
    float hi = r0 ? v[3] : v[2];
    return r1 ? hi : lo;
}

__global__ __launch_bounds__(256, 1)
void lstm_mfma_kernel(const float* __restrict__ x,
                      const float* __restrict__ W_ih,
                      const float* __restrict__ W_hh,
                      const float* __restrict__ b_ih,
                      const float* __restrict__ b_hh,
                      const float* __restrict__ W_fc,
                      const float* __restrict__ b_fc,
                      float* __restrict__ out) {
    const int tid   = threadIdx.x;
    const int lane  = tid & 63;
    const int w     = tid >> 6;        // wave -> j-slice [16w, 16w+16)
    const int q     = lane >> 4;       // k-quad / C row group
    const int m     = lane & 15;       // A row-in-tile / B col / C col
    const int b0    = m & 1;           // group0 batch (0/1)
    const int b1    = 2 + (m & 1);     // group1 batch (2/3)
    const int rho   = (m >> 1) & 3;    // replica id -> C row r to activate
    const bool r0   = (rho & 1) != 0;
    const bool r1   = (rho & 2) != 0;
    const int jmine = 16 * w + 4 * q + rho;
    const bool wr   = (m < 8);         // one writer per (j, batch) pair
    const int bbase = blockIdx.x * BT;

    __shared__ __align__(16) _Float16 hbuf[2][BT][HSTRIDE];  // h state, dbuf
    __shared__ __align__(16) float hfin[BT][LSTM_H];         // final h for FC

    // ---- weights as pinned fp16 A-fragments, log2e folded (R9 layout) ----
    int4 Ah[4][2], Ax[4];
    float4 bias4[4];
    #pragma unroll
    for (int tt = 0; tt < 4; ++tt) {
        const float sc = (tt == 2) ? L2E2 : L2E;
        const int gt = tt * 64 + 16 * w + m;
        #pragma unroll
        for (int c = 0; c < 2; ++c) {
            const float* s = W_hh + gt * LSTM_H + 32 * c + 8 * q;
            Ah[tt][c] = cvt8h(ld4(s), ld4(s + 4), sc);
            pin4(Ah[tt][c]);
        }
        float4 xa = make_float4(0.f, 0.f, 0.f, 0.f), xb = xa;
        if (q < 2) {
            const float* s = W_ih + gt * LSTM_IN + 8 * q;
            xa = ld4(s); xb = ld4(s + 4);
        }
        Ax[tt] = cvt8h(xa, xb, sc);
        pin4(Ax[tt]);
        const int gb = tt * 64 + 16 * w + 4 * q;
        float4 bi = ld4(b_ih + gb), bh = ld4(b_hh + gb);
        bias4[tt] = make_float4((bi.x + bh.x) * sc, (bi.y + bh.y) * sc,
                                (bi.z + bh.z) * sc, (bi.w + bh.w) * sc);
        pinf4(bias4[tt]);
    }

    // ---- zero hbuf[0] (h_{-1} = 0): 4 batches * 64 halves = 128 ints ----
    if (tid < 128) {
        int bb = tid >> 5, jj = tid & 31;
        reinterpret_cast<int*>(&hbuf[0][bb][0])[jj] = 0;
    }

    // ---- x streams: lane covers its group's batch, elements 8q (q<2) ----
    const float* xp0 = x + (size_t)(bbase + b0) * LSTM_T * LSTM_IN + 8 * q;
    const float* xp1 = x + (size_t)(bbase + b1) * LSTM_T * LSTM_IN + 8 * q;
    float4 z4 = make_float4(0.f, 0.f, 0.f, 0.f);
    float4 xE00 = z4, xE01 = z4, xE10 = z4, xE11 = z4;   // consumed even rounds
    float4 xO00 = z4, xO01 = z4, xO10 = z4, xO11 = z4;   // consumed odd rounds
    float4 x000 = z4, x001 = z4, x010 = z4, x011 = z4;   // x_0
    if (q < 2) {
        x000 = ld4(xp0);  x001 = ld4(xp0 + 4);
        x010 = ld4(xp1);  x011 = ld4(xp1 + 4);
    }
    floatx4 accA0[4], accA1[4], accB0[4], accB1[4];
    {   // accA = bias + W_ih . x_0 for both groups
        half8 xf0 = to_h8(x000, x001);
        half8 xf1 = to_h8(x010, x011);
        #pragma unroll
        for (int tt = 0; tt < 4; ++tt) {
            accA0[tt] = __builtin_amdgcn_mfma_f32_16x16x32_f16(
                __builtin_bit_cast(half8, Ax[tt]), xf0,
                __builtin_bit_cast(floatx4, bias4[tt]), 0, 0, 0);
            accA1[tt] = __builtin_amdgcn_mfma_f32_16x16x32_f16(
                __builtin_bit_cast(half8, Ax[tt]), xf1,
                __builtin_bit_cast(floatx4, bias4[tt]), 0, 0, 0);
        }
    }
    if (q < 2) {   // x_1 (even), x_2 (odd)
        xE00 = ld4(xp0 + LSTM_IN);      xE01 = ld4(xp0 + LSTM_IN + 4);
        xE10 = ld4(xp1 + LSTM_IN);      xE11 = ld4(xp1 + LSTM_IN + 4);
        xO00 = ld4(xp0 + 2 * LSTM_IN);  xO01 = ld4(xp0 + 2 * LSTM_IN + 4);
        xO10 = ld4(xp1 + 2 * LSTM_IN);  xO11 = ld4(xp1 + 2 * LSTM_IN + 4);
    }
    __syncthreads();   // hbuf zeros visible

    float creg0 = 0.f, hreg0 = 0.f, creg1 = 0.f, hreg1 = 0.f;

#define ACT(AIN, CREG, HREG, BOFF)                                              \
    {                                                                           \
        float gi = sigm2(sel4(AIN[0], r0, r1));                                 \
        float gf = sigm2(sel4(AIN[1], r0, r1));                                 \
        float gg = tanh2(sel4(AIN[2], r0, r1));                                 \
        float go = sigm2(sel4(AIN[3], r0, r1));                                 \
        CREG = fmaf(gf, CREG, gi * gg);                                         \
        HREG = go * tanh2(CREG * L2E2);                                         \
        if (wr) nxt[(BOFF) * HSTRIDE + jmine] = (_Float16)HREG;                 \
    }

#define ROUND(T_, XC00, XC01, XC10, XC11, AIN0, AIN1, AOUT0, AOUT1)             \
    {                                                                           \
        const _Float16* cur = &hbuf[(T_) & 1][0][0];                            \
        _Float16*       nxt = &hbuf[((T_) + 1) & 1][0][0];                      \
        /* h_{t-1} B-frags for both groups (broadcast reads, conflict-free) */  \
        half8 f00 = *reinterpret_cast<const half8*>(cur + b0 * HSTRIDE + 8 * q);      \
        half8 f01 = *reinterpret_cast<const half8*>(cur + b0 * HSTRIDE + 32 + 8 * q); \
        half8 f10 = *reinterpret_cast<const half8*>(cur + b1 * HSTRIDE + 8 * q);      \
        half8 f11 = *reinterpret_cast<const half8*>(cur + b1 * HSTRIDE + 32 + 8 * q); \
        _Pragma("unroll")                                                       \
        for (int tt = 0; tt < 4; ++tt)                                          \
            AIN0[tt] = __builtin_amdgcn_mfma_f32_16x16x32_f16(                  \
                __builtin_bit_cast(half8, Ah[tt][0]), f00, AIN0[tt], 0, 0, 0);  \
        _Pragma("unroll")                                                       \
        for (int tt = 0; tt < 4; ++tt)                                          \
            AIN0[tt] = __builtin_amdgcn_mfma_f32_16x16x32_f16(                  \
                __builtin_bit_cast(half8, Ah[tt][1]), f01, AIN0[tt], 0, 0, 0);  \
        _Pragma("unroll")                                                       \
        for (int tt = 0; tt < 4; ++tt)                                          \
            AIN1[tt] = __builtin_amdgcn_mfma_f32_16x16x32_f16(                  \
                __builtin_bit_cast(half8, Ah[tt][0]), f10, AIN1[tt], 0, 0, 0);  \
        _Pragma("unroll")                                                       \
        for (int tt = 0; tt < 4; ++tt)                                          \
            AIN1[tt] = __builtin_amdgcn_mfma_f32_16x16x32_f16(                  \
                __builtin_bit_cast(half8, Ah[tt][1]), f11, AIN1[tt], 0, 0, 0);  \
        /* activations: group0 first (its MFMAs retire first), then group1 */   \
        ACT(AIN0, creg0, hreg0, b0)                                             \
        ACT(AIN1, creg1, hreg1, b1)                                             \
        /* x-acc for step T_+1 (bias rides C operand; off the h-path) */        \
        {                                                                       \
            half8 xf0 = to_h8(XC00, XC01);                                      \
            half8 xf1 = to_h8(XC10, XC11);                                      \
            _Pragma("unroll")                                                   \
            for (int tt = 0; tt < 4; ++tt) {                                    \
                AOUT0[tt] = __builtin_amdgcn_mfma_f32_16x16x32_f16(             \
                    __builtin_bit_cast(half8, Ax[tt]), xf0,                     \
                    __builtin_bit_cast(floatx4, bias4[tt]), 0, 0, 0);           \
                AOUT1[tt] = __builtin_amdgcn_mfma_f32_16x16x32_f16(             \
                    __builtin_bit_cast(half8, Ax[tt]), xf1,                     \
                    __builtin_bit_cast(floatx4, bias4[tt]), 0, 0, 0);           \
            }                                                                   \
        }                                                                       \
        /* reload consumed regs with x_{T_+3} (2 rounds of slack) */            \
        if (q < 2 && (T_) + 3 < LSTM_T) {                                       \
            XC00 = ld4(xp0 + (size_t)((T_) + 3) * LSTM_IN);                     \
            XC01 = ld4(xp0 + (size_t)((T_) + 3) * LSTM_IN + 4);                 \
            XC10 = ld4(xp1 + (size_t)((T_) + 3) * LSTM_IN);                     \
            XC11 = ld4(xp1 + (size_t)((T_) + 3) * LSTM_IN + 4);                 \
        }                                                                       \
        lite_barrier();                                                         \
    }

    for (int t = 0; t < LSTM_T; t += 2) {
        ROUND(t,     xE00, xE01, xE10, xE11, accA0, accA1, accB0, accB1)
        ROUND(t + 1, xO00, xO01, xO10, xO11, accB0, accB1, accA0, accA1)
    }
#undef ROUND
#undef ACT

    // ---- final h (fp32) -> LDS, then FC + sigmoid ----
    if (wr) {
        hfin[b0][jmine] = hreg0;
        hfin[b1][jmine] = hreg1;
    }
    __syncthreads();

    if (tid < BT * LSTM_OUT) {
        int bb = tid >> 3, o = tid & 7;
        float s = b_fc[o];
        #pragma unroll
        for (int j4 = 0; j4 < LSTM_H / 4; ++j4) {
            float4 wv = ld4(W_fc + o * LSTM_H + 4 * j4);
            float4 hv = *reinterpret_cast<const float4*>(&hfin[bb][4 * j4]);
            s = fmaf(wv.x, hv.x, s);
            s = fmaf(wv.y, hv.y, s);
            s = fmaf(wv.z, hv.z, s);
            s = fmaf(wv.w, hv.w, s);
        }
        out[(size_t)(bbase + bb) * LSTM_OUT + o] = sigm2(s * L2E);
    }
}

extern "C" void kernel_launch(void* const* d_in, const int* in_sizes, int n_in,
                              void* d_out, int out_size, void* d_ws, size_t ws_size,
                              hipStream_t stream) {
    const float* x    = (const float*)d_in[0];
    const float* W_ih = (const float*)d_in[1];
    const float* W_hh = (const float*)d_in[2];
    const float* b_ih = (const float*)d_in[3];
    const float* b_hh = (const float*)d_in[4];
    const float* W_fc = (const float*)d_in[5];
    const float* b_fc = (const float*)d_in[6];
    float* out = (float*)d_out;

    lstm_mfma_kernel<<<1024 / BT, 256, 0, stream>>>(
        x, W_ih, W_hh, b_ih, b_hh, W_fc, b_fc, out);
}

// Round 11
// 267.966 us; speedup vs baseline: 1.3022x; 1.3022x over previous
//
#include <hip/hip_runtime.h>
#include <math.h>

// LSTM B=1024,T=512,IN=16,H=64,OUT=8, gates i,f,g,o.
// R11: R9 structure at BT=2 -> 512 blocks -> 2 INDEPENDENT blocks per CU
// (2 waves/SIMD). Model (validated on R4/R5/R8/R9/R10): round =
// perSIMD issue + chain exposed only at 1 wave/SIMD. R9 (BT=4) = 462 issue
// + ~700 exposed chain = 1163 cyc/step. R10 proved extra work in the SAME
// wave adds serially (no holes filled in-wave); hiding requires a second
// UNSYNCHRONIZED wave per SIMD: W = 2x462 ~ 924 < 1163. BT=2: the 16 MFMA
// cols hold 2 batches x 8 replicas (b=m&1, rho=(m>>1)&3, writers m<8 —
// duplicate lanes masked off the LDS write). Else identical to R9: wave w
// owns j-slice [16w,16w+16), tiles tt = gate type, fp16 weights pinned,
// h via dbuf LDS stride 72, 1 lite barrier/step, x 2 steps ahead.

#define LSTM_T 512
#define LSTM_IN 16
#define LSTM_H 64
#define LSTM_OUT 8
#define BT 2
#define HSTRIDE 72         // halves per batch row: 64 h + 8 pad (bank spread)

#define L2E   1.44269504088896340736f
#define L2E2  2.88539008177792681472f

typedef _Float16 half8  __attribute__((ext_vector_type(8)));
typedef float    floatx4 __attribute__((ext_vector_type(4)));

static __device__ __forceinline__ float fast_rcp(float x) { return __builtin_amdgcn_rcpf(x); }
static __device__ __forceinline__ float fast_exp2(float x) { return __builtin_amdgcn_exp2f(x); }
static __device__ __forceinline__ float sigm2(float p) { return fast_rcp(1.0f + fast_exp2(-p)); }
static __device__ __forceinline__ float tanh2(float p) {
    return fmaf(-2.0f, fast_rcp(1.0f + fast_exp2(p)), 1.0f);
}
static __device__ __forceinline__ void pin4(int4& v) {
    asm volatile("" : "+v"(v.x), "+v"(v.y), "+v"(v.z), "+v"(v.w));
}
static __device__ __forceinline__ void pinf4(float4& v) {
    asm volatile("" : "+v"(v.x), "+v"(v.y), "+v"(v.z), "+v"(v.w));
}
static __device__ __forceinline__ void lite_barrier() {
    asm volatile("s_waitcnt lgkmcnt(0)\n\ts_barrier" ::: "memory");
}
static __device__ __forceinline__ unsigned pk2h(float a, float b) {
    return __builtin_bit_cast(unsigned, __builtin_amdgcn_cvt_pkrtz(a, b));
}
static __device__ __forceinline__ half8 to_h8(float4 a, float4 b) {
    uint4 u = make_uint4(pk2h(a.x, a.y), pk2h(a.z, a.w), pk2h(b.x, b.y), pk2h(b.z, b.w));
    return __builtin_bit_cast(half8, u);
}
static __device__ __forceinline__ int4 cvt8h(float4 a, float4 b, float sc) {
    float4 as = make_float4(a.x * sc, a.y * sc, a.z * sc, a.w * sc);
    float4 bs = make_float4(b.x * sc, b.y * sc, b.z * sc, b.w * sc);
    return __builtin_bit_cast(int4, to_h8(as, bs));
}
static __device__ __forceinline__ float4 ld4(const float* p) {
    return *reinterpret_cast<const float4*>(p);
}
static __device__ __forceinline__ float sel4(floatx4 v, bool r0, bool r1) {
    float lo = r0 ? v[1] : v[0];
    float hi = r0 ? v[3] : v[2];
    return r1 ? hi : lo;
}

__global__ __launch_bounds__(256, 2)
void lstm_mfma_kernel(const float* __restrict__ x,
                      const float* __restrict__ W_ih,
                      const float* __restrict__ W_hh,
                      const float* __restrict__ b_ih,
                      const float* __restrict__ b_hh,
                      const float* __restrict__ W_fc,
                      const float* __restrict__ b_fc,
                      float* __restrict__ out) {
    const int tid   = threadIdx.x;
    const int lane  = tid & 63;
    const int w     = tid >> 6;        // wave -> j-slice [16w, 16w+16)
    const int q     = lane >> 4;       // k-quad / C row group
    const int m     = lane & 15;       // A row-in-tile / B col / C col
    const int b     = m & 1;           // real batch (cols = 2 b x 8 replicas)
    const int rho   = (m >> 1) & 3;    // replica id -> C row r to activate
    const bool r0   = (rho & 1) != 0;
    const bool r1   = (rho & 2) != 0;
    const int jmine = 16 * w + 4 * q + rho;   // this lane's hidden index
    const bool wr   = (m < 8);         // one writer per (j, batch) pair
    const int bbase = blockIdx.x * BT;

    __shared__ __align__(16) _Float16 hbuf[2][BT][HSTRIDE];  // h state, dbuf
    __shared__ __align__(16) float hfin[BT][LSTM_H];         // final h for FC

    // ---- weights as pinned fp16 A-fragments, log2e folded ----
    // tile tt = gate type; A row = tt*64 + 16w + m.
    int4 Ah[4][2], Ax[4];
    float4 bias4[4];
    #pragma unroll
    for (int tt = 0; tt < 4; ++tt) {
        const float sc = (tt == 2) ? L2E2 : L2E;
        const int gt = tt * 64 + 16 * w + m;
        #pragma unroll
        for (int c = 0; c < 2; ++c) {
            const float* s = W_hh + gt * LSTM_H + 32 * c + 8 * q;
            Ah[tt][c] = cvt8h(ld4(s), ld4(s + 4), sc);
            pin4(Ah[tt][c]);
        }
        float4 xa = make_float4(0.f, 0.f, 0.f, 0.f), xb = xa;
        if (q < 2) {
            const float* s = W_ih + gt * LSTM_IN + 8 * q;
            xa = ld4(s); xb = ld4(s + 4);
        }
        Ax[tt] = cvt8h(xa, xb, sc);
        pin4(Ax[tt]);
        const int gb = tt * 64 + 16 * w + 4 * q;
        float4 bi = ld4(b_ih + gb), bh = ld4(b_hh + gb);
        bias4[tt] = make_float4((bi.x + bh.x) * sc, (bi.y + bh.y) * sc,
                                (bi.z + bh.z) * sc, (bi.w + bh.w) * sc);
        pinf4(bias4[tt]);
    }

    // ---- zero hbuf[0] h-region (h_{-1} = 0): 2 batches * 64 halves = 64 ints ----
    if (tid < 64) {
        int bb = tid >> 5, jj = tid & 31;
        reinterpret_cast<int*>(&hbuf[0][bb][0])[jj] = 0;
    }

    // ---- x: lane covers batch b, elements 8q..8q+7 (q<2 real) ----
    const float* xp = x + (size_t)(bbase + b) * LSTM_T * LSTM_IN + 8 * q;
    float4 xA0 = make_float4(0.f, 0.f, 0.f, 0.f), xA1 = xA0;  // even steps
    float4 xB0 = xA0, xB1 = xA0;                              // odd steps
    if (q < 2) {
        xA0 = ld4(xp);              xA1 = ld4(xp + 4);               // x_0
        xB0 = ld4(xp + LSTM_IN);    xB1 = ld4(xp + LSTM_IN + 4);     // x_1
    }
    __syncthreads();   // hbuf zeros visible

    float creg = 0.0f, hreg = 0.0f;

#define STEP(T_, X0, X1)                                                        \
    {                                                                           \
        const _Float16* cur = &hbuf[(T_) & 1][0][0];                            \
        _Float16*       nxt = &hbuf[((T_) + 1) & 1][0][0];                      \
        /* h_{t-1} B-frags (col m -> batch b) */                                \
        half8 bh0 = *reinterpret_cast<const half8*>(cur + b * HSTRIDE + 8 * q); \
        half8 bh1 = *reinterpret_cast<const half8*>(cur + b * HSTRIDE + 32 + 8 * q); \
        /* acc = bias + W_ih . x_t (independent of h -> hides under ds_read) */ \
        half8 xf = to_h8(X0, X1);                                               \
        floatx4 acc[4];                                                         \
        _Pragma("unroll")                                                       \
        for (int tt = 0; tt < 4; ++tt)                                          \
            acc[tt] = __builtin_amdgcn_mfma_f32_16x16x32_f16(                   \
                __builtin_bit_cast(half8, Ax[tt]), xf,                          \
                __builtin_bit_cast(floatx4, bias4[tt]), 0, 0, 0);               \
        /* reload this reg set with x_{t+2} (2 steps of slack) */               \
        if (q < 2 && (T_) + 2 < LSTM_T) {                                       \
            X0 = ld4(xp + (size_t)((T_) + 2) * LSTM_IN);                        \
            X1 = ld4(xp + (size_t)((T_) + 2) * LSTM_IN + 4);                    \
        }                                                                       \
        _Pragma("unroll")                                                       \
        for (int tt = 0; tt < 4; ++tt)                                          \
            acc[tt] = __builtin_amdgcn_mfma_f32_16x16x32_f16(                   \
                __builtin_bit_cast(half8, Ah[tt][0]), bh0, acc[tt], 0, 0, 0);   \
        _Pragma("unroll")                                                       \
        for (int tt = 0; tt < 4; ++tt)                                          \
            acc[tt] = __builtin_amdgcn_mfma_f32_16x16x32_f16(                   \
                __builtin_bit_cast(half8, Ah[tt][1]), bh1, acc[tt], 0, 0, 0);   \
        /* replica rho activates ONLY row r=rho: 1 (j,b) pair per lane */       \
        float gi = sigm2(sel4(acc[0], r0, r1));                                 \
        float gf = sigm2(sel4(acc[1], r0, r1));                                 \
        float gg = tanh2(sel4(acc[2], r0, r1));                                 \
        float go = sigm2(sel4(acc[3], r0, r1));                                 \
        creg = fmaf(gf, creg, gi * gg);                                         \
        hreg = go * tanh2(creg * L2E2);                                         \
        /* h -> next buffer: duplicate replica lanes (m>=8) masked off */       \
        if (wr) nxt[b * HSTRIDE + jmine] = (_Float16)hreg;                      \
        lite_barrier();                                                         \
    }

    for (int t = 0; t < LSTM_T; t += 2) {
        STEP(t,     xA0, xA1)
        STEP(t + 1, xB0, xB1)
    }
#undef STEP

    // ---- final h (fp32) -> LDS, then FC + sigmoid ----
    if (wr) hfin[b][jmine] = hreg;
    __syncthreads();

    if (tid < BT * LSTM_OUT) {
        int bb = tid >> 3, o = tid & 7;
        float s = b_fc[o];
        #pragma unroll
        for (int j4 = 0; j4 < LSTM_H / 4; ++j4) {
            float4 wv = ld4(W_fc + o * LSTM_H + 4 * j4);
            float4 hv = *reinterpret_cast<const float4*>(&hfin[bb][4 * j4]);
            s = fmaf(wv.x, hv.x, s);
            s = fmaf(wv.y, hv.y, s);
            s = fmaf(wv.z, hv.z, s);
            s = fmaf(wv.w, hv.w, s);
        }
        out[(size_t)(bbase + bb) * LSTM_OUT + o] = sigm2(s * L2E);
    }
}

extern "C" void kernel_launch(void* const* d_in, const int* in_sizes, int n_in,
                              void* d_out, int out_size, void* d_ws, size_t ws_size,
                              hipStream_t stream) {
    const float* x    = (const float*)d_in[0];
    const float* W_ih = (const float*)d_in[1];
    const float* W_hh = (const float*)d_in[2];
    const float* b_ih = (const float*)d_in[3];
    const float* b_hh = (const float*)d_in[4];
    const float* W_fc = (const float*)d_in[5];
    const float* b_fc = (const float*)d_in[6];
    float* out = (float*)d_out;

    lstm_mfma_kernel<<<1024 / BT, 256, 0, stream>>>(
        x, W_ih, W_hh, b_ih, b_hh, W_fc, b_fc, out);
}

// Round 12
// 260.236 us; speedup vs baseline: 1.3409x; 1.0297x over previous
//
#include <hip/hip_runtime.h>
#include <math.h>

// LSTM B=1024,T=512,IN=16,H=64,OUT=8, gates i,f,g,o.
// R12: GATE-PAIRING on R11. R9(1163)/R11(1116) proved wall = 512 x serial
// chain at any occupancy; chain includes 8-10 quarter-rate trans (16cyc
// wave-issue) serialized before c. The 8 duplicate lanes (m>=8, previously
// redundant) now evaluate tanh(g)/sigma(o) while m<8 evaluates
// sigma(f)/sigma(i): both are a + b*rcp(1+exp2(s*u)) with per-lane
// (s,a,b) -> ONE exp2+rcp serves two gates. Results return via 2
// ds_swizzle lane^8 (intra-wave, exact, no barrier). Trans 10 -> 6/step.
// Else identical to R11: BT=2, 512 blocks (2/CU), wave w owns j-slice
// [16w,16w+16), tiles tt = gate type, fp16 weights pinned (unscaled now),
// h via dbuf LDS stride 72, 1 lite barrier/step, x 2 steps ahead.

#define LSTM_T 512
#define LSTM_IN 16
#define LSTM_H 64
#define LSTM_OUT 8
#define BT 2
#define HSTRIDE 72         // halves per batch row: 64 h + 8 pad (bank spread)

#define L2E   1.44269504088896340736f
#define L2E2  2.88539008177792681472f

typedef _Float16 half8  __attribute__((ext_vector_type(8)));
typedef float    floatx4 __attribute__((ext_vector_type(4)));

static __device__ __forceinline__ float fast_rcp(float x) { return __builtin_amdgcn_rcpf(x); }
static __device__ __forceinline__ float fast_exp2(float x) { return __builtin_amdgcn_exp2f(x); }
// p pre-scaled by log2e:
static __device__ __forceinline__ float sigm2(float p) { return fast_rcp(1.0f + fast_exp2(-p)); }
// p pre-scaled by 2*log2e:
static __device__ __forceinline__ float tanh2(float p) {
    return fmaf(-2.0f, fast_rcp(1.0f + fast_exp2(p)), 1.0f);
}
static __device__ __forceinline__ void pin4(int4& v) {
    asm volatile("" : "+v"(v.x), "+v"(v.y), "+v"(v.z), "+v"(v.w));
}
static __device__ __forceinline__ void pinf4(float4& v) {
    asm volatile("" : "+v"(v.x), "+v"(v.y), "+v"(v.z), "+v"(v.w));
}
static __device__ __forceinline__ void lite_barrier() {
    asm volatile("s_waitcnt lgkmcnt(0)\n\ts_barrier" ::: "memory");
}
static __device__ __forceinline__ unsigned pk2h(float a, float b) {
    return __builtin_bit_cast(unsigned, __builtin_amdgcn_cvt_pkrtz(a, b));
}
static __device__ __forceinline__ half8 to_h8(float4 a, float4 b) {
    uint4 u = make_uint4(pk2h(a.x, a.y), pk2h(a.z, a.w), pk2h(b.x, b.y), pk2h(b.z, b.w));
    return __builtin_bit_cast(half8, u);
}
static __device__ __forceinline__ int4 cvt8h(float4 a, float4 b) {
    return __builtin_bit_cast(int4, to_h8(a, b));
}
static __device__ __forceinline__ float4 ld4(const float* p) {
    return *reinterpret_cast<const float4*>(p);
}
static __device__ __forceinline__ float sel4(floatx4 v, bool r0, bool r1) {
    float lo = r0 ? v[1] : v[0];
    float hi = r0 ? v[3] : v[2];
    return r1 ? hi : lo;
}
// exchange with lane^8 (BitMode offset = xor 8<<10 | and 0x1F); pairs
// (m, m+8) sit in the same 32-lane group so wave64 halves are safe.
static __device__ __forceinline__ float swz8(float v) {
    int r = __builtin_amdgcn_ds_swizzle(__builtin_bit_cast(int, v), 0x201F);
    return __builtin_bit_cast(float, r);
}

__global__ __launch_bounds__(256, 2)
void lstm_mfma_kernel(const float* __restrict__ x,
                      const float* __restrict__ W_ih,
                      const float* __restrict__ W_hh,
                      const float* __restrict__ b_ih,
                      const float* __restrict__ b_hh,
                      const float* __restrict__ W_fc,
                      const float* __restrict__ b_fc,
                      float* __restrict__ out) {
    const int tid   = threadIdx.x;
    const int lane  = tid & 63;
    const int w     = tid >> 6;        // wave -> j-slice [16w, 16w+16)
    const int q     = lane >> 4;       // k-quad / C row group
    const int m     = lane & 15;       // A row-in-tile / B col / C col
    const int b     = m & 1;           // real batch (cols = 2 b x 8 replicas)
    const int rho   = (m >> 1) & 3;    // replica id -> C row r to activate
    const bool r0   = (rho & 1) != 0;
    const bool r1   = (rho & 2) != 0;
    const bool h1   = (m & 8) != 0;    // gate-pair half: 0 = f/i, 1 = g/o
    const int jmine = 16 * w + 4 * q + rho;   // this lane's hidden index
    const bool wr   = (m < 8);         // writers = half0 (valid c/h state)
    const int bbase = blockIdx.x * BT;

    // unified activation act(u) = a1 + b1 * rcp(1 + exp2(s1*u)):
    //   half0 (sigma): s=-L2E, a=0, b=+1 ;  half1 eval1 (tanh): s=L2E2, a=1, b=-2
    const float s1 = h1 ? L2E2 : -L2E;
    const float a1 = h1 ? 1.0f : 0.0f;
    const float b1 = h1 ? -2.0f : 1.0f;

    __shared__ __align__(16) _Float16 hbuf[2][BT][HSTRIDE];  // h state, dbuf
    __shared__ __align__(16) float hfin[BT][LSTM_H];         // final h for FC

    // ---- weights as pinned fp16 A-fragments (UNSCALED) ----
    // tile tt = gate type (0=i,1=f,2=g,3=o); A row = tt*64 + 16w + m.
    int4 Ah[4][2], Ax[4];
    float4 bias4[4];
    #pragma unroll
    for (int tt = 0; tt < 4; ++tt) {
        const int gt = tt * 64 + 16 * w + m;
        #pragma unroll
        for (int c = 0; c < 2; ++c) {
            const float* s = W_hh + gt * LSTM_H + 32 * c + 8 * q;
            Ah[tt][c] = cvt8h(ld4(s), ld4(s + 4));
            pin4(Ah[tt][c]);
        }
        float4 xa = make_float4(0.f, 0.f, 0.f, 0.f), xb = xa;
        if (q < 2) {
            const float* s = W_ih + gt * LSTM_IN + 8 * q;
            xa = ld4(s); xb = ld4(s + 4);
        }
        Ax[tt] = cvt8h(xa, xb);
        pin4(Ax[tt]);
        const int gb = tt * 64 + 16 * w + 4 * q;
        float4 bi = ld4(b_ih + gb), bh = ld4(b_hh + gb);
        bias4[tt] = make_float4(bi.x + bh.x, bi.y + bh.y, bi.z + bh.z, bi.w + bh.w);
        pinf4(bias4[tt]);
    }

    // ---- zero hbuf[0] h-region (h_{-1} = 0): 2 batches * 64 halves ----
    if (tid < 64) {
        int bb = tid >> 5, jj = tid & 31;
        reinterpret_cast<int*>(&hbuf[0][bb][0])[jj] = 0;
    }

    // ---- x: lane covers batch b, elements 8q..8q+7 (q<2 real) ----
    const float* xp = x + (size_t)(bbase + b) * LSTM_T * LSTM_IN + 8 * q;
    float4 xA0 = make_float4(0.f, 0.f, 0.f, 0.f), xA1 = xA0;  // even steps
    float4 xB0 = xA0, xB1 = xA0;                              // odd steps
    if (q < 2) {
        xA0 = ld4(xp);              xA1 = ld4(xp + 4);               // x_0
        xB0 = ld4(xp + LSTM_IN);    xB1 = ld4(xp + LSTM_IN + 4);     // x_1
    }
    __syncthreads();   // hbuf zeros visible

    float creg = 0.0f, hreg = 0.0f;

#define STEP(T_, X0, X1)                                                        \
    {                                                                           \
        const _Float16* cur = &hbuf[(T_) & 1][0][0];                            \
        _Float16*       nxt = &hbuf[((T_) + 1) & 1][0][0];                      \
        /* h_{t-1} B-frags (col m -> batch b): issue first, fill with x-MFMA */ \
        half8 bh0 = *reinterpret_cast<const half8*>(cur + b * HSTRIDE + 8 * q); \
        half8 bh1 = *reinterpret_cast<const half8*>(cur + b * HSTRIDE + 32 + 8 * q); \
        half8 xf = to_h8(X0, X1);                                               \
        floatx4 acc[4];                                                         \
        _Pragma("unroll")                                                       \
        for (int tt = 0; tt < 4; ++tt)                                          \
            acc[tt] = __builtin_amdgcn_mfma_f32_16x16x32_f16(                   \
                __builtin_bit_cast(half8, Ax[tt]), xf,                          \
                __builtin_bit_cast(floatx4, bias4[tt]), 0, 0, 0);               \
        /* reload this reg set with x_{t+2} (2 steps of slack) */               \
        if (q < 2 && (T_) + 2 < LSTM_T) {                                       \
            X0 = ld4(xp + (size_t)((T_) + 2) * LSTM_IN);                        \
            X1 = ld4(xp + (size_t)((T_) + 2) * LSTM_IN + 4);                    \
        }                                                                       \
        _Pragma("unroll")                                                       \
        for (int tt = 0; tt < 4; ++tt)                                          \
            acc[tt] = __builtin_amdgcn_mfma_f32_16x16x32_f16(                   \
                __builtin_bit_cast(half8, Ah[tt][0]), bh0, acc[tt], 0, 0, 0);   \
        _Pragma("unroll")                                                       \
        for (int tt = 0; tt < 4; ++tt)                                          \
            acc[tt] = __builtin_amdgcn_mfma_f32_16x16x32_f16(                   \
                __builtin_bit_cast(half8, Ah[tt][1]), bh1, acc[tt], 0, 0, 0);   \
        /* gate-paired preacts: eval1 = f|g, eval2 = i|o (half0|half1) */       \
        floatx4 v1, v2;                                                         \
        _Pragma("unroll")                                                       \
        for (int r = 0; r < 4; ++r) {                                           \
            v1[r] = h1 ? acc[2][r] : acc[1][r];                                 \
            v2[r] = h1 ? acc[3][r] : acc[0][r];                                 \
        }                                                                       \
        float u1 = sel4(v1, r0, r1);                                            \
        float u2 = sel4(v2, r0, r1);                                            \
        /* unified act: one exp2+rcp serves sigma(half0) AND tanh(half1) */     \
        float act1 = fmaf(b1, fast_rcp(1.0f + fast_exp2(s1 * u1)), a1);         \
        float act2 = fast_rcp(1.0f + fast_exp2(-L2E * u2));  /* sigma always */ \
        /* swap with partner lane^8: half0 receives tanh(g), sigma(o) */        \
        float g_in = swz8(act1);                                                \
        float o_in = swz8(act2);                                                \
        /* state update: valid on half0 (half1 garbage is benign, no NaN) */    \
        creg = fmaf(act1, creg, act2 * g_in);     /* f*c + i*g   */             \
        hreg = o_in * tanh2(creg * L2E2);         /* o * tanh(c) */             \
        if (wr) nxt[b * HSTRIDE + jmine] = (_Float16)hreg;                      \
        lite_barrier();                                                         \
    }

    for (int t = 0; t < LSTM_T; t += 2) {
        STEP(t,     xA0, xA1)
        STEP(t + 1, xB0, xB1)
    }
#undef STEP

    // ---- final h (fp32) -> LDS, then FC + sigmoid ----
    if (wr) hfin[b][jmine] = hreg;
    __syncthreads();

    if (tid < BT * LSTM_OUT) {
        int bb = tid >> 3, o = tid & 7;
        float s = b_fc[o];
        #pragma unroll
        for (int j4 = 0; j4 < LSTM_H / 4; ++j4) {
            float4 wv = ld4(W_fc + o * LSTM_H + 4 * j4);
            float4 hv = *reinterpret_cast<const float4*>(&hfin[bb][4 * j4]);
            s = fmaf(wv.x, hv.x, s);
            s = fmaf(wv.y, hv.y, s);
            s = fmaf(wv.z, hv.z, s);
            s = fmaf(wv.w, hv.w, s);
        }
        out[(size_t)(bbase + bb) * LSTM_OUT + o] = sigm2(s * L2E);
    }
}

extern "C" void kernel_launch(void* const* d_in, const int* in_sizes, int n_in,
                              void* d_out, int out_size, void* d_ws, size_t ws_size,
                              hipStream_t stream) {
    const float* x    = (const float*)d_in[0];
    const float* W_ih = (const float*)d_in[1];
    const float* W_hh = (const float*)d_in[2];
    const float* b_ih = (const float*)d_in[3];
    const float* b_hh = (const float*)d_in[4];
    const float* W_fc = (const float*)d_in[5];
    const float* b_fc = (const float*)d_in[6];
    float* out = (float*)d_out;

    lstm_mfma_kernel<<<1024 / BT, 256, 0, stream>>>(
        x, W_ih, W_hh, b_ih, b_hh, W_fc, b_fc, out);
}